// Round 14
// baseline (945.573 us; speedup 1.0000x reference)
//
#include <hip/hip_runtime.h>
#include <hip/hip_bf16.h>
#include <hip/hip_cooperative_groups.h>
#include <stdint.h>

namespace cg = cooperative_groups;

#define N_NODES 50000
#define N_EDGES 800000
#define D_IN    128
#define H_DIM   256
#define BN_EPS  1e-5f
#define LN_EPS  1e-5f
#define NBLK_SCAN 196  // ceil(50000/256)
#define PREP_BLOCKS 512
#define SLICE_ELEMS ((size_t)N_NODES * 32)  // ushort elems per 32-col slice
#define EDGE_CHUNK 3072

// workspace offsets (bytes)
#define OFF_CNT    0         // 200000
#define OFF_BN0S   200000    // [4][128] f32
#define OFF_BN0Q   202048
#define OFF_S1     204096    // [4][256] f32
#define OFF_Q1     208192
#define OFF_S2     212288
#define OFF_Q2     216384
#define OFF_DHIST  220480    // 64 ints
#define ZERO_BYTES 220736
#define OFF_DCUR   220736
#define OFF_BSUM   220992
#define OFF_BPRE   222016
#define OFF_DINV   223040
#define OFF_OFFS   423040
#define OFF_CURS   623104
#define OFF_PERM   823104
#define OFF_RANK   1023104
#define OFF_EDGES  1223104   // 1.6 MB ushort, 64B aligned
#define OFF_XT     2823168
#define OFF_W1T    15623168
#define OFF_W2T    15688704
#define OFF_HLIN   15819776
#define OFF_GBUF   41419776
#define OFF_H1     67019776

typedef float v4f __attribute__((ext_vector_type(4)));
typedef short v8s __attribute__((ext_vector_type(8)));

__device__ __forceinline__ float bflo(unsigned u){ return __uint_as_float(u << 16); }
__device__ __forceinline__ float bfhi(unsigned u){ return __uint_as_float(u & 0xffff0000u); }
__device__ __forceinline__ unsigned short f2bf(float f){
  unsigned u = __float_as_uint(f);
  u += 0x7fffu + ((u >> 16) & 1u);
  return (unsigned short)(u >> 16);
}
__device__ __forceinline__ unsigned pack2(float a, float b){
  return (unsigned)f2bf(a) | ((unsigned)f2bf(b) << 16);
}
__device__ __forceinline__ float wred(float v){
  #pragma unroll
  for (int m = 1; m < 64; m <<= 1) v += __shfl_xor(v, m, 64);
  return v;
}

// in-block (256 threads) exclusive scan of one int per thread (block-uniform call sites only)
__device__ __forceinline__ int block_excl_scan(int v){
  int t = threadIdx.x;
  int lane = t & 63, w = t >> 6;
  int inc = v;
  #pragma unroll
  for (int m = 1; m < 64; m <<= 1){
    int o = __shfl_up(inc, m, 64);
    if (lane >= m) inc += o;
  }
  __shared__ int wsum[4];
  if (lane == 63) wsum[w] = inc;
  __syncthreads();
  int base = 0;
  #pragma unroll
  for (int j = 0; j < 4; ++j) if (j < w) base += wsum[j];
  return base + inc - v;  // exclusive
}

// ================= cooperative preprocessing mega-kernel =================
// Replaces: memset, deg, hist, dscan, dperm, blocksum, bscan, cscan, csr,
// bn0stats, prepx, transpose2  (12 dispatches -> 1)
__global__ __launch_bounds__(256) void prep_k(const int* ei, const float* x,
                                              const float* fs, const float* fb,
                                              const float* bn0g, const float* bn0b,
                                              const float* W1, const float* W2,
                                              char* w){
  cg::grid_group grid = cg::this_grid();
  int b = blockIdx.x, t = threadIdx.x;
  int*   cnt   = (int*)(w + OFF_CNT);
  float* bn0S  = (float*)(w + OFF_BN0S);
  float* bn0Q  = (float*)(w + OFF_BN0Q);
  int*   dhist = (int*)(w + OFF_DHIST);
  int*   dcur  = (int*)(w + OFF_DCUR);
  int*   bsum  = (int*)(w + OFF_BSUM);
  int*   bpre  = (int*)(w + OFF_BPRE);
  float* dinv  = (float*)(w + OFF_DINV);
  int*   offs  = (int*)(w + OFF_OFFS);
  int*   curs  = (int*)(w + OFF_CURS);
  int*   perm  = (int*)(w + OFF_PERM);
  int*   rank  = (int*)(w + OFF_RANK);
  unsigned short* edges = (unsigned short*)(w + OFF_EDGES);
  unsigned short* xt  = (unsigned short*)(w + OFF_XT);
  unsigned short* W1t = (unsigned short*)(w + OFF_W1T);
  unsigned short* W2t = (unsigned short*)(w + OFF_W2T);

  __shared__ float red[256][8];
  __shared__ int lh[64], lb[64], lc[64];
  __shared__ int ws4[4];

  // ---- phase 0: zero the accumulator region ----
  {
    int* z = (int*)w;
    const int n = ZERO_BYTES / 4;
    for (int i = b * 256 + t; i < n; i += PREP_BLOCKS * 256) z[i] = 0;
  }
  grid.sync();

  // ---- phase 1: bn0stats (blocks 0..127)  ||  degree count (blocks 128..511) ----
  if (b < 128){
    int cl = t & 31, rg = t >> 5;
    int c = cl * 4;
    float4 fs4 = *(const float4*)(fs + c);
    float4 fb4 = *(const float4*)(fb + c);
    float s0=0,s1=0,s2=0,s3=0,q0=0,q1=0,q2=0,q3=0;
    for (int row = b * 8 + rg; row < N_NODES; row += 128 * 8){
      float4 xv = *(const float4*)(x + (size_t)row * D_IN + c);
      float v0 = xv.x * fs4.x + fb4.x;
      float v1 = xv.y * fs4.y + fb4.y;
      float v2 = xv.z * fs4.z + fb4.z;
      float v3 = xv.w * fs4.w + fb4.w;
      s0 += v0; s1 += v1; s2 += v2; s3 += v3;
      q0 += v0*v0; q1 += v1*v1; q2 += v2*v2; q3 += v3*v3;
    }
    red[t][0]=s0; red[t][1]=s1; red[t][2]=s2; red[t][3]=s3;
    red[t][4]=q0; red[t][5]=q1; red[t][6]=q2; red[t][7]=q3;
    __syncthreads();
    float* Sr = bn0S + (b & 3) * D_IN;
    float* Qr = bn0Q + (b & 3) * D_IN;
    if (t < 32){
      float a[8];
      #pragma unroll
      for (int i = 0; i < 8; ++i) a[i] = red[t][i];
      for (int j = 1; j < 8; ++j)
        #pragma unroll
        for (int i = 0; i < 8; ++i) a[i] += red[t + 32*j][i];
      #pragma unroll
      for (int i = 0; i < 4; ++i){ atomicAdd(&Sr[t*4+i], a[i]); atomicAdd(&Qr[t*4+i], a[4+i]); }
    }
  } else {
    for (int e = (b - 128) * 256 + t; e < N_EDGES; e += (PREP_BLOCKS - 128) * 256)
      atomicAdd(&cnt[ei[N_EDGES + e]], 1);
  }
  grid.sync();

  // ---- phase 2: degree histogram (blocks 0..31) ----
  if (b < 32){
    if (t < 64) lh[t] = 0;
    __syncthreads();
    for (int i = b * 256 + t; i < N_NODES; i += 32 * 256)
      atomicAdd(&lh[min(cnt[i], 63)], 1);
    __syncthreads();
    if (t < 64 && lh[t] > 0) atomicAdd(&dhist[t], lh[t]);
  }
  grid.sync();

  // ---- phase 3: 64-bin exclusive scan (block 0) ----
  if (b == 0 && t < 64){
    int v = dhist[t];
    int inc = v;
    #pragma unroll
    for (int m = 1; m < 64; m <<= 1){
      int o = __shfl_up(inc, m, 64);
      if (t >= m) inc += o;
    }
    dcur[t] = inc - v;
  }
  grid.sync();

  // ---- phase 4: counting-sort scatter (blocks 0..31) ----
  if (b < 32){
    if (t < 64){ lh[t] = 0; lc[t] = 0; }
    __syncthreads();
    for (int i = b * 256 + t; i < N_NODES; i += 32 * 256)
      atomicAdd(&lh[min(cnt[i], 63)], 1);
    __syncthreads();
    if (t < 64 && lh[t] > 0) lb[t] = atomicAdd(&dcur[t], lh[t]);
    __syncthreads();
    for (int i = b * 256 + t; i < N_NODES; i += 32 * 256){
      int bin = min(cnt[i], 63);
      int r = atomicAdd(&lc[bin], 1);
      int pos = lb[bin] + r;
      perm[pos] = i;
      rank[i] = pos;
    }
  }
  grid.sync();

  // ---- phase 5: blocksum+transpose (blocks 0..195)  ||  prepx (blocks 196..511) ----
  if (b < NBLK_SCAN){
    int i = b * 256 + t;
    int v = (i < N_NODES) ? cnt[perm[i]] : 0;
    #pragma unroll
    for (int m = 1; m < 64; m <<= 1) v += __shfl_xor(v, m, 64);
    if ((t & 63) == 0) ws4[t >> 6] = v;
    __syncthreads();
    if (t == 0) bsum[b] = ws4[0] + ws4[1] + ws4[2] + ws4[3];
    for (int i2 = b * 256 + t; i2 < D_IN * H_DIM; i2 += NBLK_SCAN * 256){
      int r = i2 / H_DIM, c = i2 % H_DIM;
      W1t[c * D_IN + r] = f2bf(W1[i2]);
    }
    for (int i2 = b * 256 + t; i2 < H_DIM * H_DIM; i2 += NBLK_SCAN * 256){
      int r = i2 / H_DIM, c = i2 % H_DIM;
      W2t[c * H_DIM + r] = f2bf(W2[i2]);
    }
  } else {
    for (int i = (b - NBLK_SCAN) * 256 + t; i < N_NODES * 32; i += (PREP_BLOCKS - NBLK_SCAN) * 256){
      int row = i >> 5; int c = (i & 31) * 4;
      float4 Sv = *(const float4*)(bn0S + c);
      float4 Qv = *(const float4*)(bn0Q + c);
      #pragma unroll
      for (int rep = 1; rep < 4; ++rep){
        float4 s2 = *(const float4*)(bn0S + rep * D_IN + c);
        float4 q2 = *(const float4*)(bn0Q + rep * D_IN + c);
        Sv.x += s2.x; Sv.y += s2.y; Sv.z += s2.z; Sv.w += s2.w;
        Qv.x += q2.x; Qv.y += q2.y; Qv.z += q2.z; Qv.w += q2.w;
      }
      float4 fs4 = *(const float4*)(fs + c);
      float4 fb4 = *(const float4*)(fb + c);
      float4 gg4 = *(const float4*)(bn0g + c);
      float4 bb4 = *(const float4*)(bn0b + c);
      const float invN = 1.0f / N_NODES;
      float mu0 = Sv.x*invN, mu1 = Sv.y*invN, mu2 = Sv.z*invN, mu3 = Sv.w*invN;
      float r0 = rsqrtf(Qv.x*invN - mu0*mu0 + BN_EPS);
      float r1 = rsqrtf(Qv.y*invN - mu1*mu1 + BN_EPS);
      float r2 = rsqrtf(Qv.z*invN - mu2*mu2 + BN_EPS);
      float r3 = rsqrtf(Qv.w*invN - mu3*mu3 + BN_EPS);
      float a0 = gg4.x*r0*fs4.x, c0 = gg4.x*r0*(fb4.x - mu0) + bb4.x;
      float a1 = gg4.y*r1*fs4.y, c1 = gg4.y*r1*(fb4.y - mu1) + bb4.y;
      float a2 = gg4.z*r2*fs4.z, c2 = gg4.z*r2*(fb4.z - mu2) + bb4.z;
      float a3 = gg4.w*r3*fs4.w, c3 = gg4.w*r3*(fb4.w - mu3) + bb4.w;
      float4 xv = *(const float4*)(x + (size_t)row * D_IN + c);
      uint2 o;
      o.x = pack2(a0 * xv.x + c0, a1 * xv.y + c1);
      o.y = pack2(a2 * xv.z + c2, a3 * xv.w + c3);
      *(uint2*)(xt + (size_t)row * D_IN + c) = o;
    }
  }
  grid.sync();

  // ---- phase 6: scan of block sums (block 0) ----
  if (b == 0){
    int v = (t < NBLK_SCAN) ? bsum[t] : 0;
    int e = block_excl_scan(v);
    if (t < NBLK_SCAN) bpre[t] = e;
    if (t == 0) offs[N_NODES] = N_EDGES;
  }
  grid.sync();

  // ---- phase 7: offsets/cursors + dinv (blocks 0..195) ----
  if (b < NBLK_SCAN){
    int i = b * 256 + t;
    int node = 0, v = 0;
    if (i < N_NODES){ node = perm[i]; v = cnt[node]; }
    int e = block_excl_scan(v) + bpre[b];
    if (i < N_NODES){
      offs[i] = e; curs[i] = e;
      dinv[node] = rsqrtf((float)v + 1.0f);
    }
  }
  grid.sync();

  // ---- phase 8: CSR scatter (all blocks) ----
  for (int e = b * 256 + t; e < N_EDGES; e += PREP_BLOCKS * 256){
    int s = ei[e], d = ei[N_EDGES + e];
    int p = atomicAdd(&curs[rank[d]], 1);
    edges[p] = (unsigned short)s;
  }
}

// ---------------- bf16 MFMA GEMM: 64x256 tile, C = dinv[row]*(A@Bt^T), slice-major ----------------
template<int K>
__global__ __launch_bounds__(256) void gemm_k(const unsigned short* A, const unsigned short* Bt,
                                              const float* dinv, unsigned short* C, int M){
  __shared__ __align__(16) short smem[16896];
  __shared__ float dvs[64];
  short* As = smem;               // [64][40]
  short* Bs = smem + 64 * 40;     // [256][40]
  int t = threadIdx.x;
  int m0 = blockIdx.x * 64;
  int lane = t & 63;
  int w = t >> 6;                 // wave -> col block w*64
  int fr = lane & 15, quad = lane >> 4;
  if (t < 64) dvs[t] = (m0 + t < M) ? dinv[m0 + t] : 0.0f;
  v4f acc[4][4] = {};
  int sr = t >> 2;                // 0..63
  int sk = (t & 3) << 3;          // 0,8,16,24
  for (int k0 = 0; k0 < K; k0 += 32){
    __syncthreads();
    uint4 av = {0,0,0,0};
    int arow = m0 + sr;
    if (arow < M) av = *(const uint4*)(A + (size_t)arow * K + k0 + sk);
    *(uint4*)(&As[sr * 40 + sk]) = av;
    #pragma unroll
    for (int j = 0; j < 4; ++j){
      int brow = sr + 64 * j;
      uint4 bv = *(const uint4*)(Bt + (size_t)brow * K + k0 + sk);
      *(uint4*)(&Bs[brow * 40 + sk]) = bv;
    }
    __syncthreads();
    v8s af[4], bf[4];
    #pragma unroll
    for (int mi = 0; mi < 4; ++mi)
      af[mi] = *(const v8s*)(&As[(mi * 16 + fr) * 40 + quad * 8]);
    #pragma unroll
    for (int ni = 0; ni < 4; ++ni)
      bf[ni] = *(const v8s*)(&Bs[(w * 64 + ni * 16 + fr) * 40 + quad * 8]);
    #pragma unroll
    for (int mi = 0; mi < 4; ++mi)
      #pragma unroll
      for (int ni = 0; ni < 4; ++ni)
        acc[mi][ni] = __builtin_amdgcn_mfma_f32_16x16x32_bf16(af[mi], bf[ni], acc[mi][ni], 0, 0, 0);
  }
  __syncthreads();
  short* Cs = smem; // [64][264]
  #pragma unroll
  for (int mi = 0; mi < 4; ++mi)
    #pragma unroll
    for (int ni = 0; ni < 4; ++ni)
      #pragma unroll
      for (int r = 0; r < 4; ++r){
        int row = mi * 16 + quad * 4 + r;
        int col = w * 64 + ni * 16 + fr;
        Cs[row * 264 + col] = (short)f2bf(acc[mi][ni][r] * dvs[row]);
      }
  __syncthreads();
  int orow = t >> 2;
  int grow = m0 + orow;
  if (grow < M){
    #pragma unroll
    for (int j = 0; j < 4; ++j){
      int oc = (t & 3) * 16 + 64 * j;
      v8s v0 = *(const v8s*)(&Cs[orow * 264 + oc]);
      v8s v1 = *(const v8s*)(&Cs[orow * 264 + oc + 8]);
      *(v8s*)(&C[(size_t)(oc >> 5) * SLICE_ELEMS + (size_t)grow * 32 + (oc & 31)]) = v0;
      int oc1 = oc + 8;
      *(v8s*)(&C[(size_t)(oc1 >> 5) * SLICE_ELEMS + (size_t)grow * 32 + (oc1 & 31)]) = v1;
    }
  }
}

// ---------------- edge aggregation: XCD-sliced, LDS-staged 2B descriptors ----------------
// hs rows are PRE-SCALED by dinv[src]; g[d] = relu(dinv[d]*(sum_e hs[src] + hs[d]) + b)
__global__ __launch_bounds__(256) void agg_k(const unsigned short* hs, const int* offsets,
                                             const unsigned short* edges, const int* perm,
                                             const float* dinv, const float* bias,
                                             unsigned short* g){
  __shared__ unsigned eds32[EDGE_CHUNK / 2];
  int t = threadIdx.x;
  int lane = t & 63;
  int slice = blockIdx.x & 7;
  int l8 = lane & 7;
  int nb = (blockIdx.x >> 3) * 32;
  int idx = nb + (t >> 3);
  int lastn = min(nb + 32, N_NODES);
  int blk0 = offsets[nb];
  int base = blk0 & ~1;
  int blkN = offsets[lastn];
  const unsigned* gsrc = (const unsigned*)(edges + base);
  int nu = min((blkN - base + 1) >> 1, EDGE_CHUNK / 2);
  for (int i = t; i < nu; i += 256)
    eds32[i] = gsrc[i];
  __syncthreads();
  if (idx >= N_NODES) return;
  int node = perm[idx];
  const unsigned short* hb = hs + (size_t)slice * SLICE_ELEMS;
  float4 bb = *(const float4*)(bias + slice * 32 + l8 * 4);
  uint2 sv = *(const uint2*)(hb + (size_t)node * 32 + l8 * 4);
  float a0 = bflo(sv.x), a1 = bfhi(sv.x);
  float a2 = bflo(sv.y), a3 = bfhi(sv.y);
  int e  = offsets[idx];
  int e1 = offsets[idx + 1];
  if ((e & 1) && e < e1){
    int ru = (e - base) >> 1;
    unsigned d = (ru < EDGE_CHUNK / 2) ? eds32[ru] : gsrc[ru];
    unsigned s = d >> 16;
    uint2 v = *(const uint2*)(hb + (size_t)s * 32 + l8 * 4);
    a0 += bflo(v.x); a1 += bfhi(v.x);
    a2 += bflo(v.y); a3 += bfhi(v.y);
    ++e;
  }
  for (; e + 8 <= e1; e += 8){
    int ru = (e - base) >> 1;
    unsigned d0, d1, d2, d3;
    if (ru + 4 <= EDGE_CHUNK / 2){
      d0 = eds32[ru]; d1 = eds32[ru + 1]; d2 = eds32[ru + 2]; d3 = eds32[ru + 3];
    } else {
      d0 = gsrc[ru]; d1 = gsrc[ru + 1]; d2 = gsrc[ru + 2]; d3 = gsrc[ru + 3];
    }
    uint2 v0 = *(const uint2*)(hb + (size_t)(d0 & 0xffffu) * 32 + l8 * 4);
    uint2 v1 = *(const uint2*)(hb + (size_t)(d0 >> 16)     * 32 + l8 * 4);
    uint2 v2 = *(const uint2*)(hb + (size_t)(d1 & 0xffffu) * 32 + l8 * 4);
    uint2 v3 = *(const uint2*)(hb + (size_t)(d1 >> 16)     * 32 + l8 * 4);
    uint2 v4 = *(const uint2*)(hb + (size_t)(d2 & 0xffffu) * 32 + l8 * 4);
    uint2 v5 = *(const uint2*)(hb + (size_t)(d2 >> 16)     * 32 + l8 * 4);
    uint2 v6 = *(const uint2*)(hb + (size_t)(d3 & 0xffffu) * 32 + l8 * 4);
    uint2 v7 = *(const uint2*)(hb + (size_t)(d3 >> 16)     * 32 + l8 * 4);
    a0 += bflo(v0.x) + bflo(v1.x) + bflo(v2.x) + bflo(v3.x)
        + bflo(v4.x) + bflo(v5.x) + bflo(v6.x) + bflo(v7.x);
    a1 += bfhi(v0.x) + bfhi(v1.x) + bfhi(v2.x) + bfhi(v3.x)
        + bfhi(v4.x) + bfhi(v5.x) + bfhi(v6.x) + bfhi(v7.x);
    a2 += bflo(v0.y) + bflo(v1.y) + bflo(v2.y) + bflo(v3.y)
        + bflo(v4.y) + bflo(v5.y) + bflo(v6.y) + bflo(v7.y);
    a3 += bfhi(v0.y) + bfhi(v1.y) + bfhi(v2.y) + bfhi(v3.y)
        + bfhi(v4.y) + bfhi(v5.y) + bfhi(v6.y) + bfhi(v7.y);
  }
  for (; e < e1; ++e){
    int r = e - base;
    unsigned d = ((r >> 1) < EDGE_CHUNK / 2) ? eds32[r >> 1] : gsrc[r >> 1];
    unsigned s = (r & 1) ? (d >> 16) : (d & 0xffffu);
    uint2 v = *(const uint2*)(hb + (size_t)s * 32 + l8 * 4);
    a0 += bflo(v.x); a1 += bfhi(v.x);
    a2 += bflo(v.y); a3 += bfhi(v.y);
  }
  float dv = dinv[node];
  uint2 o;
  o.x = pack2(fmaxf(dv * a0 + bb.x, 0.f), fmaxf(dv * a1 + bb.y, 0.f));
  o.y = pack2(fmaxf(dv * a2 + bb.z, 0.f), fmaxf(dv * a3 + bb.w, 0.f));
  *(uint2*)(g + (size_t)node * H_DIM + slice * 32 + l8 * 4) = o;
}

// ---------------- column stats over g (bf16 [N,256]), 4 S/Q replicas ----------------
__global__ __launch_bounds__(256) void colstats_k(const unsigned short* g, float* S, float* Q){
  int t = threadIdx.x;
  int cl = t & 63, rg = t >> 6;
  int c = cl * 4;
  float s0=0,s1=0,s2=0,s3=0,q0=0,q1=0,q2=0,q3=0;
  for (int row = blockIdx.x * 4 + rg; row < N_NODES; row += gridDim.x * 4){
    uint2 u = *(const uint2*)(g + (size_t)row * H_DIM + c);
    float v0 = bflo(u.x), v1 = bfhi(u.x), v2 = bflo(u.y), v3 = bfhi(u.y);
    s0 += v0; s1 += v1; s2 += v2; s3 += v3;
    q0 += v0*v0; q1 += v1*v1; q2 += v2*v2; q3 += v3*v3;
  }
  __shared__ float red[256][8];
  red[t][0]=s0; red[t][1]=s1; red[t][2]=s2; red[t][3]=s3;
  red[t][4]=q0; red[t][5]=q1; red[t][6]=q2; red[t][7]=q3;
  __syncthreads();
  float* Sr = S + (blockIdx.x & 3) * H_DIM;
  float* Qr = Q + (blockIdx.x & 3) * H_DIM;
  if (t < 64){
    float a[8];
    #pragma unroll
    for (int i = 0; i < 8; ++i) a[i] = red[t][i];
    for (int j = 1; j < 4; ++j)
      #pragma unroll
      for (int i = 0; i < 8; ++i) a[i] += red[t + 64*j][i];
    #pragma unroll
    for (int i = 0; i < 4; ++i){ atomicAdd(&Sr[t*4+i], a[i]); atomicAdd(&Qr[t*4+i], a[4+i]); }
  }
}

// per-thread BN finalize from raw stats (sums 4 replicas) for this thread's 4 columns
__device__ __forceinline__ void bn_coeffs(const float* S, const float* Q,
                                          const float* gg, const float* bb, int c,
                                          float4& sc, float4& sh){
  float4 Sv = *(const float4*)(S + c);
  float4 Qv = *(const float4*)(Q + c);
  #pragma unroll
  for (int rep = 1; rep < 4; ++rep){
    float4 s2 = *(const float4*)(S + rep * H_DIM + c);
    float4 q2 = *(const float4*)(Q + rep * H_DIM + c);
    Sv.x += s2.x; Sv.y += s2.y; Sv.z += s2.z; Sv.w += s2.w;
    Qv.x += q2.x; Qv.y += q2.y; Qv.z += q2.z; Qv.w += q2.w;
  }
  float4 g4 = *(const float4*)(gg + c);
  float4 b4 = *(const float4*)(bb + c);
  const float invN = 1.0f / N_NODES;
  float mu0 = Sv.x*invN, mu1 = Sv.y*invN, mu2 = Sv.z*invN, mu3 = Sv.w*invN;
  sc.x = g4.x * rsqrtf(Qv.x*invN - mu0*mu0 + BN_EPS);
  sc.y = g4.y * rsqrtf(Qv.y*invN - mu1*mu1 + BN_EPS);
  sc.z = g4.z * rsqrtf(Qv.z*invN - mu2*mu2 + BN_EPS);
  sc.w = g4.w * rsqrtf(Qv.w*invN - mu3*mu3 + BN_EPS);
  sh.x = b4.x - sc.x * mu0; sh.y = b4.y - sc.y * mu1;
  sh.z = b4.z - sc.z * mu2; sh.w = b4.w - sc.w * mu3;
}

// ---------------- BN + LN apply (layer 1): h1 = LN(BN(g)) ----------------
__global__ __launch_bounds__(256) void apply1_k(const unsigned short* g, const float* S, const float* Q,
                                                const float* bng, const float* bnb,
                                                const float* lng, const float* lnb, unsigned short* h1){
  int lane = threadIdx.x & 63;
  int row = blockIdx.x * 4 + (threadIdx.x >> 6);
  if (row >= N_NODES) return;
  int c = lane * 4;
  float4 s4, h4;
  bn_coeffs(S, Q, bng, bnb, c, s4, h4);
  uint2 u = *(const uint2*)(g + (size_t)row * H_DIM + c);
  float v0 = s4.x * bflo(u.x) + h4.x;
  float v1 = s4.y * bfhi(u.x) + h4.y;
  float v2 = s4.z * bflo(u.y) + h4.z;
  float v3 = s4.w * bfhi(u.y) + h4.w;
  float sum = wred(v0 + v1 + v2 + v3);
  float sq  = wred(v0*v0 + v1*v1 + v2*v2 + v3*v3);
  float mu = sum * (1.0f / H_DIM);
  float var = sq * (1.0f / H_DIM) - mu * mu;
  float rs = rsqrtf(var + LN_EPS);
  float4 g4 = *(const float4*)(lng + c);
  float4 b4 = *(const float4*)(lnb + c);
  float y0 = g4.x * (v0 - mu) * rs + b4.x;
  float y1 = g4.y * (v1 - mu) * rs + b4.y;
  float y2 = g4.z * (v2 - mu) * rs + b4.z;
  float y3 = g4.w * (v3 - mu) * rs + b4.w;
  uint2 o; o.x = pack2(y0, y1); o.y = pack2(y2, y3);
  *(uint2*)(h1 + (size_t)row * H_DIM + c) = o;
}

// ---------------- layer 2 apply + residual + output GEMM ----------------
__global__ __launch_bounds__(256) void apply2_k(const unsigned short* g, const float* S, const float* Q,
                                                const float* bng, const float* bnb,
                                                const float* lng, const float* lnb,
                                                const unsigned short* h1, const float* Wout,
                                                const float* bout, float* out){
  int lane = threadIdx.x & 63;
  int row = blockIdx.x * 4 + (threadIdx.x >> 6);
  if (row >= N_NODES) return;
  int c = lane * 4;
  float4 s4, h4;
  bn_coeffs(S, Q, bng, bnb, c, s4, h4);
  uint2 u = *(const uint2*)(g + (size_t)row * H_DIM + c);
  float v0 = s4.x * bflo(u.x) + h4.x;
  float v1 = s4.y * bfhi(u.x) + h4.y;
  float v2 = s4.z * bflo(u.y) + h4.z;
  float v3 = s4.w * bfhi(u.y) + h4.w;
  float sum = wred(v0 + v1 + v2 + v3);
  float sq  = wred(v0*v0 + v1*v1 + v2*v2 + v3*v3);
  float mu = sum * (1.0f / H_DIM);
  float var = sq * (1.0f / H_DIM) - mu * mu;
  float rs = rsqrtf(var + LN_EPS);
  float4 g4 = *(const float4*)(lng + c);
  float4 b4 = *(const float4*)(lnb + c);
  uint2 hr = *(const uint2*)(h1 + (size_t)row * H_DIM + c);
  float y0 = g4.x * (v0 - mu) * rs + b4.x + bflo(hr.x);
  float y1 = g4.y * (v1 - mu) * rs + b4.y + bfhi(hr.x);
  float y2 = g4.z * (v2 - mu) * rs + b4.z + bflo(hr.y);
  float y3 = g4.w * (v3 - mu) * rs + b4.w + bfhi(hr.y);
  float4 w0 = *(const float4*)(Wout + c * 2);
  float4 w1 = *(const float4*)(Wout + c * 2 + 4);
  float o0 = y0 * w0.x + y1 * w0.z + y2 * w1.x + y3 * w1.z;
  float o1 = y0 * w0.y + y1 * w0.w + y2 * w1.y + y3 * w1.w;
  o0 = wred(o0); o1 = wred(o1);
  if (lane == 0){
    out[(size_t)row * 2 + 0] = o0 + bout[0];
    out[(size_t)row * 2 + 1] = o1 + bout[1];
  }
}

extern "C" void kernel_launch(void* const* d_in, const int* in_sizes, int n_in,
                              void* d_out, int out_size, void* d_ws, size_t ws_size,
                              hipStream_t stream) {
  const float* x    = (const float*)d_in[0];
  const int*   ei   = (const int*)d_in[1];
  const float* fs   = (const float*)d_in[2];
  const float* fb   = (const float*)d_in[3];
  const float* bn0g = (const float*)d_in[4];
  const float* bn0b = (const float*)d_in[5];
  const float* W1   = (const float*)d_in[6];
  const float* b1   = (const float*)d_in[7];
  const float* bn1g = (const float*)d_in[8];
  const float* bn1b = (const float*)d_in[9];
  const float* ln1g = (const float*)d_in[10];
  const float* ln1b = (const float*)d_in[11];
  const float* W2   = (const float*)d_in[12];
  const float* b2   = (const float*)d_in[13];
  const float* bn2g = (const float*)d_in[14];
  const float* bn2b = (const float*)d_in[15];
  const float* ln2g = (const float*)d_in[16];
  const float* ln2b = (const float*)d_in[17];
  const float* Wout = (const float*)d_in[18];
  const float* bout = (const float*)d_in[19];
  float* out = (float*)d_out;

  char* w = (char*)d_ws;
  float* S1    = (float*)(w + OFF_S1);
  float* Q1    = (float*)(w + OFF_Q1);
  float* S2    = (float*)(w + OFF_S2);
  float* Q2    = (float*)(w + OFF_Q2);
  float* dinv  = (float*)(w + OFF_DINV);
  int*   offs  = (int*)(w + OFF_OFFS);
  int*   perm  = (int*)(w + OFF_PERM);
  unsigned short* edges = (unsigned short*)(w + OFF_EDGES);
  unsigned short* xt   = (unsigned short*)(w + OFF_XT);
  unsigned short* W1t  = (unsigned short*)(w + OFF_W1T);
  unsigned short* W2t  = (unsigned short*)(w + OFF_W2T);
  unsigned short* hlin = (unsigned short*)(w + OFF_HLIN);
  unsigned short* gbuf = (unsigned short*)(w + OFF_GBUF);
  unsigned short* h1   = (unsigned short*)(w + OFF_H1);

  (void)in_sizes; (void)n_in; (void)out_size; (void)ws_size;

  // one cooperative kernel replaces the entire preprocessing + input-transform chain
  {
    void* args[] = { (void*)&ei, (void*)&x, (void*)&fs, (void*)&fb,
                     (void*)&bn0g, (void*)&bn0b, (void*)&W1, (void*)&W2, (void*)&w };
    hipLaunchCooperativeKernel((const void*)prep_k, dim3(PREP_BLOCKS), dim3(256),
                               args, 0, stream);
  }

  int ggrid = (N_NODES + 63) / 64;
  int agg_blocks = ((N_NODES + 31) / 32) * 8;

  // ---- layer 1 ----
  gemm_k<D_IN><<<ggrid, 256, 0, stream>>>(xt, W1t, dinv, hlin, N_NODES);
  agg_k<<<agg_blocks, 256, 0, stream>>>(hlin, offs, edges, perm, dinv, b1, gbuf);
  colstats_k<<<104, 256, 0, stream>>>(gbuf, S1, Q1);
  apply1_k<<<(N_NODES + 3) / 4, 256, 0, stream>>>(gbuf, S1, Q1, bn1g, bn1b, ln1g, ln1b, h1);

  // ---- layer 2 ----
  gemm_k<H_DIM><<<ggrid, 256, 0, stream>>>(h1, W2t, dinv, hlin, N_NODES);
  agg_k<<<agg_blocks, 256, 0, stream>>>(hlin, offs, edges, perm, dinv, b2, gbuf);
  colstats_k<<<104, 256, 0, stream>>>(gbuf, S2, Q2);
  apply2_k<<<(N_NODES + 3) / 4, 256, 0, stream>>>(gbuf, S2, Q2, bn2g, bn2b, ln2g, ln2b, h1, Wout, bout, out);
}

// Round 15
// 429.244 us; speedup vs baseline: 2.2029x; 2.2029x over previous
//
#include <hip/hip_runtime.h>
#include <hip/hip_bf16.h>
#include <stdint.h>

#define N_NODES 50000
#define N_EDGES 800000
#define D_IN    128
#define H_DIM   256
#define BN_EPS  1e-5f
#define LN_EPS  1e-5f
#define NBLK_SCAN 196  // ceil(50000/256)
#define NBLK_HIST 32
#define NBLK2 1563     // ceil(50000/32) node-groups for agg
#define SLICE_ELEMS ((size_t)N_NODES * 32)
#define EDGE_CHUNK 3072

typedef float v4f __attribute__((ext_vector_type(4)));
typedef short v8s __attribute__((ext_vector_type(8)));

__device__ __forceinline__ float bflo(unsigned u){ return __uint_as_float(u << 16); }
__device__ __forceinline__ float bfhi(unsigned u){ return __uint_as_float(u & 0xffff0000u); }
__device__ __forceinline__ unsigned short f2bf(float f){
  unsigned u = __float_as_uint(f);
  u += 0x7fffu + ((u >> 16) & 1u);
  return (unsigned short)(u >> 16);
}
__device__ __forceinline__ unsigned pack2(float a, float b){
  return (unsigned)f2bf(a) | ((unsigned)f2bf(b) << 16);
}
__device__ __forceinline__ float wred(float v){
  #pragma unroll
  for (int m = 1; m < 64; m <<= 1) v += __shfl_xor(v, m, 64);
  return v;
}

__device__ __forceinline__ int block_excl_scan(int v){
  int t = threadIdx.x;
  int lane = t & 63, w = t >> 6;
  int inc = v;
  #pragma unroll
  for (int m = 1; m < 64; m <<= 1){
    int o = __shfl_up(inc, m, 64);
    if (lane >= m) inc += o;
  }
  __shared__ int wsum[4];
  if (lane == 63) wsum[w] = inc;
  __syncthreads();
  int base = 0;
  #pragma unroll
  for (int j = 0; j < 4; ++j) if (j < w) base += wsum[j];
  return base + inc - v;  // exclusive
}

// ---------------- degree / degree-sort / CSR ----------------
__global__ void deg_k(const int* ei, int* cnt){
  int e = blockIdx.x * 256 + threadIdx.x;
  if (e < N_EDGES) atomicAdd(&cnt[ei[N_EDGES + e]], 1);
}

__global__ __launch_bounds__(256) void hist_k(const int* cnt, int* dhist){
  __shared__ int lh[64];
  int t = threadIdx.x;
  if (t < 64) lh[t] = 0;
  __syncthreads();
  for (int i = blockIdx.x * 256 + t; i < N_NODES; i += NBLK_HIST * 256)
    atomicAdd(&lh[min(cnt[i], 63)], 1);
  __syncthreads();
  if (t < 64 && lh[t] > 0) atomicAdd(&dhist[t], lh[t]);
}

__global__ void dscan_k(const int* dhist, int* dcur){
  int t = threadIdx.x; // 64
  int v = dhist[t];
  int inc = v;
  #pragma unroll
  for (int m = 1; m < 64; m <<= 1){
    int o = __shfl_up(inc, m, 64);
    if (t >= m) inc += o;
  }
  dcur[t] = inc - v;
}

__global__ __launch_bounds__(256) void dperm_k(const int* cnt, int* dcur, int* perm, int* rank){
  __shared__ int lh[64], lb[64], lc[64];
  int t = threadIdx.x;
  if (t < 64){ lh[t] = 0; lc[t] = 0; }
  __syncthreads();
  for (int i = blockIdx.x * 256 + t; i < N_NODES; i += NBLK_HIST * 256)
    atomicAdd(&lh[min(cnt[i], 63)], 1);
  __syncthreads();
  if (t < 64 && lh[t] > 0) lb[t] = atomicAdd(&dcur[t], lh[t]);
  __syncthreads();
  for (int i = blockIdx.x * 256 + t; i < N_NODES; i += NBLK_HIST * 256){
    int b = min(cnt[i], 63);
    int r = atomicAdd(&lc[b], 1);
    int pos = lb[b] + r;
    perm[pos] = i;
    rank[i] = pos;
  }
}

__global__ __launch_bounds__(256) void blocksum_k(const int* cnt, const int* perm, int* bsum){
  int i = blockIdx.x * 256 + threadIdx.x;
  int v = (i < N_NODES) ? cnt[perm[i]] : 0;
  #pragma unroll
  for (int m = 1; m < 64; m <<= 1) v += __shfl_xor(v, m, 64);
  __shared__ int ws[4];
  int t = threadIdx.x;
  if ((t & 63) == 0) ws[t >> 6] = v;
  __syncthreads();
  if (t == 0) bsum[blockIdx.x] = ws[0] + ws[1] + ws[2] + ws[3];
}

__global__ __launch_bounds__(256) void bscan_k(const int* bsum, int* bpre, int* offs){
  int t = threadIdx.x;
  int v = (t < NBLK_SCAN) ? bsum[t] : 0;
  int e = block_excl_scan(v);
  if (t < NBLK_SCAN) bpre[t] = e;
  if (t == 0) offs[N_NODES] = N_EDGES;
}

__global__ __launch_bounds__(256) void cscan_k(const int* cnt, const int* perm, const int* bpre,
                                               int* offs, int* curs, float* dinv){
  int t = threadIdx.x;
  int i = blockIdx.x * 256 + t;
  int node = 0, v = 0;
  if (i < N_NODES){ node = perm[i]; v = cnt[node]; }
  int e = block_excl_scan(v) + bpre[blockIdx.x];
  if (i < N_NODES){
    offs[i] = e; curs[i] = e;
    dinv[node] = rsqrtf((float)v + 1.0f);
  }
}

__global__ void csr_k(const int* ei, const int* rank, int* cursor, unsigned short* edges){
  int e = blockIdx.x * 256 + threadIdx.x;
  if (e >= N_EDGES) return;
  int s = ei[e], d = ei[N_EDGES + e];
  int p = atomicAdd(&cursor[rank[d]], 1);
  edges[p] = (unsigned short)s;
}

// ---------------- BN0 stats, 4 S/Q replicas ----------------
__global__ __launch_bounds__(256) void bn0stats_k(const float* x, const float* fs, const float* fb,
                                                  float* S, float* Q){
  int t = threadIdx.x;
  int cl = t & 31, rg = t >> 5;
  int c = cl * 4;
  float4 fs4 = *(const float4*)(fs + c);
  float4 fb4 = *(const float4*)(fb + c);
  float s0=0,s1=0,s2=0,s3=0,q0=0,q1=0,q2=0,q3=0;
  for (int row = blockIdx.x * 8 + rg; row < N_NODES; row += gridDim.x * 8){
    float4 xv = *(const float4*)(x + (size_t)row * D_IN + c);
    float v0 = xv.x * fs4.x + fb4.x;
    float v1 = xv.y * fs4.y + fb4.y;
    float v2 = xv.z * fs4.z + fb4.z;
    float v3 = xv.w * fs4.w + fb4.w;
    s0 += v0; s1 += v1; s2 += v2; s3 += v3;
    q0 += v0*v0; q1 += v1*v1; q2 += v2*v2; q3 += v3*v3;
  }
  __shared__ float red[256][8];
  red[t][0]=s0; red[t][1]=s1; red[t][2]=s2; red[t][3]=s3;
  red[t][4]=q0; red[t][5]=q1; red[t][6]=q2; red[t][7]=q3;
  __syncthreads();
  float* Sr = S + (blockIdx.x & 3) * D_IN;
  float* Qr = Q + (blockIdx.x & 3) * D_IN;
  if (t < 32){
    float a[8];
    #pragma unroll
    for (int i = 0; i < 8; ++i) a[i] = red[t][i];
    for (int j = 1; j < 8; ++j)
      #pragma unroll
      for (int i = 0; i < 8; ++i) a[i] += red[t + 32*j][i];
    #pragma unroll
    for (int i = 0; i < 4; ++i){ atomicAdd(&Sr[t*4+i], a[i]); atomicAdd(&Qr[t*4+i], a[4+i]); }
  }
}

__global__ __launch_bounds__(256) void prepx_k(const float* x, const float* S, const float* Q,
                                               const float* fs, const float* fb,
                                               const float* gg, const float* bb,
                                               unsigned short* xt){
  int i = blockIdx.x * 256 + threadIdx.x;
  int row = i >> 5; int c = (i & 31) * 4;
  float4 Sv = *(const float4*)(S + c);
  float4 Qv = *(const float4*)(Q + c);
  #pragma unroll
  for (int rep = 1; rep < 4; ++rep){
    float4 s2 = *(const float4*)(S + rep * D_IN + c);
    float4 q2 = *(const float4*)(Q + rep * D_IN + c);
    Sv.x += s2.x; Sv.y += s2.y; Sv.z += s2.z; Sv.w += s2.w;
    Qv.x += q2.x; Qv.y += q2.y; Qv.z += q2.z; Qv.w += q2.w;
  }
  float4 fs4 = *(const float4*)(fs + c);
  float4 fb4 = *(const float4*)(fb + c);
  float4 gg4 = *(const float4*)(gg + c);
  float4 bb4 = *(const float4*)(bb + c);
  const float invN = 1.0f / N_NODES;
  float mu0 = Sv.x*invN, mu1 = Sv.y*invN, mu2 = Sv.z*invN, mu3 = Sv.w*invN;
  float r0 = rsqrtf(Qv.x*invN - mu0*mu0 + BN_EPS);
  float r1 = rsqrtf(Qv.y*invN - mu1*mu1 + BN_EPS);
  float r2 = rsqrtf(Qv.z*invN - mu2*mu2 + BN_EPS);
  float r3 = rsqrtf(Qv.w*invN - mu3*mu3 + BN_EPS);
  float a0 = gg4.x*r0*fs4.x, b0 = gg4.x*r0*(fb4.x - mu0) + bb4.x;
  float a1 = gg4.y*r1*fs4.y, b1 = gg4.y*r1*(fb4.y - mu1) + bb4.y;
  float a2 = gg4.z*r2*fs4.z, b2 = gg4.z*r2*(fb4.z - mu2) + bb4.z;
  float a3 = gg4.w*r3*fs4.w, b3 = gg4.w*r3*(fb4.w - mu3) + bb4.w;
  float4 xv = *(const float4*)(x + (size_t)row * D_IN + c);
  uint2 o;
  o.x = pack2(a0 * xv.x + b0, a1 * xv.y + b1);
  o.y = pack2(a2 * xv.z + b2, a3 * xv.w + b3);
  *(uint2*)(xt + (size_t)row * D_IN + c) = o;
}

__global__ void transpose2_k(const float* W1, const float* W2,
                             unsigned short* W1t, unsigned short* W2t){
  int i = blockIdx.x * 256 + threadIdx.x;
  if (i < D_IN * H_DIM){
    int r = i / H_DIM, c = i % H_DIM;
    W1t[c * D_IN + r] = f2bf(W1[i]);
  }
  if (i < H_DIM * H_DIM){
    int r = i / H_DIM, c = i % H_DIM;
    W2t[c * H_DIM + r] = f2bf(W2[i]);
  }
}

// ---------------- bf16 MFMA GEMM: 64x256 tile, C = dinv[row]*(A@Bt^T), slice-major ----------------
template<int K>
__global__ __launch_bounds__(256) void gemm_k(const unsigned short* A, const unsigned short* Bt,
                                              const float* dinv, unsigned short* C, int M){
  __shared__ __align__(16) short smem[16896];
  __shared__ float dvs[64];
  short* As = smem;               // [64][40]
  short* Bs = smem + 64 * 40;     // [256][40]
  int t = threadIdx.x;
  int m0 = blockIdx.x * 64;
  int lane = t & 63;
  int w = t >> 6;
  int fr = lane & 15, quad = lane >> 4;
  if (t < 64) dvs[t] = (m0 + t < M) ? dinv[m0 + t] : 0.0f;
  v4f acc[4][4] = {};
  int sr = t >> 2;
  int sk = (t & 3) << 3;
  for (int k0 = 0; k0 < K; k0 += 32){
    __syncthreads();
    uint4 av = {0,0,0,0};
    int arow = m0 + sr;
    if (arow < M) av = *(const uint4*)(A + (size_t)arow * K + k0 + sk);
    *(uint4*)(&As[sr * 40 + sk]) = av;
    #pragma unroll
    for (int j = 0; j < 4; ++j){
      int brow = sr + 64 * j;
      uint4 bv = *(const uint4*)(Bt + (size_t)brow * K + k0 + sk);
      *(uint4*)(&Bs[brow * 40 + sk]) = bv;
    }
    __syncthreads();
    v8s af[4], bf[4];
    #pragma unroll
    for (int mi = 0; mi < 4; ++mi)
      af[mi] = *(const v8s*)(&As[(mi * 16 + fr) * 40 + quad * 8]);
    #pragma unroll
    for (int ni = 0; ni < 4; ++ni)
      bf[ni] = *(const v8s*)(&Bs[(w * 64 + ni * 16 + fr) * 40 + quad * 8]);
    #pragma unroll
    for (int mi = 0; mi < 4; ++mi)
      #pragma unroll
      for (int ni = 0; ni < 4; ++ni)
        acc[mi][ni] = __builtin_amdgcn_mfma_f32_16x16x32_bf16(af[mi], bf[ni], acc[mi][ni], 0, 0, 0);
  }
  __syncthreads();
  short* Cs = smem; // [64][264]
  #pragma unroll
  for (int mi = 0; mi < 4; ++mi)
    #pragma unroll
    for (int ni = 0; ni < 4; ++ni)
      #pragma unroll
      for (int r = 0; r < 4; ++r){
        int row = mi * 16 + quad * 4 + r;
        int col = w * 64 + ni * 16 + fr;
        Cs[row * 264 + col] = (short)f2bf(acc[mi][ni][r] * dvs[row]);
      }
  __syncthreads();
  int orow = t >> 2;
  int grow = m0 + orow;
  if (grow < M){
    #pragma unroll
    for (int j = 0; j < 4; ++j){
      int oc = (t & 3) * 16 + 64 * j;
      v8s v0 = *(const v8s*)(&Cs[orow * 264 + oc]);
      v8s v1 = *(const v8s*)(&Cs[orow * 264 + oc + 8]);
      *(v8s*)(&C[(size_t)(oc >> 5) * SLICE_ELEMS + (size_t)grow * 32 + (oc & 31)]) = v0;
      int oc1 = oc + 8;
      *(v8s*)(&C[(size_t)(oc1 >> 5) * SLICE_ELEMS + (size_t)grow * 32 + (oc1 & 31)]) = v1;
    }
  }
}

// ---------------- edge aggregation + fused column-stat partials ----------------
// hs rows PRE-SCALED by dinv[src]; g[d] = relu(dinv[d]*(sum_e hs[src] + hs[d]) + b).
// Epilogue: block-local column sums (S,Q) over its 32 nodes -> pS/pQ[blockIdx*32+col32]
__global__ __launch_bounds__(256) void agg_k(const unsigned short* hs, const int* offsets,
                                             const unsigned short* edges, const int* perm,
                                             const float* dinv, const float* bias,
                                             unsigned short* g, float* pS, float* pQ){
  __shared__ unsigned eds32[EDGE_CHUNK / 2];
  __shared__ float wps[4][8][8];  // [wave][l8][0..3 S, 4..7 Q]
  int t = threadIdx.x;
  int lane = t & 63;
  int wv = t >> 6;
  int slice = blockIdx.x & 7;
  int l8 = lane & 7;
  int nb = (blockIdx.x >> 3) * 32;
  int idx = nb + (t >> 3);
  int lastn = min(nb + 32, N_NODES);
  int blk0 = offsets[nb];
  int base = blk0 & ~1;
  int blkN = offsets[lastn];
  const unsigned* gsrc = (const unsigned*)(edges + base);
  int nu = min((blkN - base + 1) >> 1, EDGE_CHUNK / 2);
  for (int i = t; i < nu; i += 256)
    eds32[i] = gsrc[i];
  __syncthreads();
  bool act = idx < N_NODES;
  int node = act ? perm[idx] : 0;
  const unsigned short* hb = hs + (size_t)slice * SLICE_ELEMS;
  float4 bb = *(const float4*)(bias + slice * 32 + l8 * 4);
  uint2 sv = *(const uint2*)(hb + (size_t)node * 32 + l8 * 4);
  float a0 = bflo(sv.x), a1 = bfhi(sv.x);
  float a2 = bflo(sv.y), a3 = bfhi(sv.y);
  int e  = act ? offsets[idx] : 0;
  int e1 = act ? offsets[idx + 1] : 0;
  if ((e & 1) && e < e1){
    int ru = (e - base) >> 1;
    unsigned d = (ru < EDGE_CHUNK / 2) ? eds32[ru] : gsrc[ru];
    unsigned s = d >> 16;
    uint2 v = *(const uint2*)(hb + (size_t)s * 32 + l8 * 4);
    a0 += bflo(v.x); a1 += bfhi(v.x);
    a2 += bflo(v.y); a3 += bfhi(v.y);
    ++e;
  }
  for (; e + 8 <= e1; e += 8){
    int ru = (e - base) >> 1;
    unsigned d0, d1, d2, d3;
    if (ru + 4 <= EDGE_CHUNK / 2){
      d0 = eds32[ru]; d1 = eds32[ru + 1]; d2 = eds32[ru + 2]; d3 = eds32[ru + 3];
    } else {
      d0 = gsrc[ru]; d1 = gsrc[ru + 1]; d2 = gsrc[ru + 2]; d3 = gsrc[ru + 3];
    }
    uint2 v0 = *(const uint2*)(hb + (size_t)(d0 & 0xffffu) * 32 + l8 * 4);
    uint2 v1 = *(const uint2*)(hb + (size_t)(d0 >> 16)     * 32 + l8 * 4);
    uint2 v2 = *(const uint2*)(hb + (size_t)(d1 & 0xffffu) * 32 + l8 * 4);
    uint2 v3 = *(const uint2*)(hb + (size_t)(d1 >> 16)     * 32 + l8 * 4);
    uint2 v4 = *(const uint2*)(hb + (size_t)(d2 & 0xffffu) * 32 + l8 * 4);
    uint2 v5 = *(const uint2*)(hb + (size_t)(d2 >> 16)     * 32 + l8 * 4);
    uint2 v6 = *(const uint2*)(hb + (size_t)(d3 & 0xffffu) * 32 + l8 * 4);
    uint2 v7 = *(const uint2*)(hb + (size_t)(d3 >> 16)     * 32 + l8 * 4);
    a0 += bflo(v0.x) + bflo(v1.x) + bflo(v2.x) + bflo(v3.x)
        + bflo(v4.x) + bflo(v5.x) + bflo(v6.x) + bflo(v7.x);
    a1 += bfhi(v0.x) + bfhi(v1.x) + bfhi(v2.x) + bfhi(v3.x)
        + bfhi(v4.x) + bfhi(v5.x) + bfhi(v6.x) + bfhi(v7.x);
    a2 += bflo(v0.y) + bflo(v1.y) + bflo(v2.y) + bflo(v3.y)
        + bflo(v4.y) + bflo(v5.y) + bflo(v6.y) + bflo(v7.y);
    a3 += bfhi(v0.y) + bfhi(v1.y) + bfhi(v2.y) + bfhi(v3.y)
        + bfhi(v4.y) + bfhi(v5.y) + bfhi(v6.y) + bfhi(v7.y);
  }
  for (; e < e1; ++e){
    int r = e - base;
    unsigned d = ((r >> 1) < EDGE_CHUNK / 2) ? eds32[r >> 1] : gsrc[r >> 1];
    unsigned s = (r & 1) ? (d >> 16) : (d & 0xffffu);
    uint2 v = *(const uint2*)(hb + (size_t)s * 32 + l8 * 4);
    a0 += bflo(v.x); a1 += bfhi(v.x);
    a2 += bflo(v.y); a3 += bfhi(v.y);
  }
  float dv = dinv[node];
  float y0 = act ? fmaxf(dv * a0 + bb.x, 0.f) : 0.f;
  float y1 = act ? fmaxf(dv * a1 + bb.y, 0.f) : 0.f;
  float y2 = act ? fmaxf(dv * a2 + bb.z, 0.f) : 0.f;
  float y3 = act ? fmaxf(dv * a3 + bb.w, 0.f) : 0.f;
  if (act){
    uint2 o;
    o.x = pack2(y0, y1); o.y = pack2(y2, y3);
    *(uint2*)(g + (size_t)node * H_DIM + slice * 32 + l8 * 4) = o;
  }
  // column partials: reduce over the wave's 8 node-groups (lane bits 3..5)
  float q0 = y0*y0, q1 = y1*y1, q2 = y2*y2, q3 = y3*y3;
  #pragma unroll
  for (int m = 8; m < 64; m <<= 1){
    y0 += __shfl_xor(y0, m, 64); y1 += __shfl_xor(y1, m, 64);
    y2 += __shfl_xor(y2, m, 64); y3 += __shfl_xor(y3, m, 64);
    q0 += __shfl_xor(q0, m, 64); q1 += __shfl_xor(q1, m, 64);
    q2 += __shfl_xor(q2, m, 64); q3 += __shfl_xor(q3, m, 64);
  }
  if (lane < 8){
    wps[wv][l8][0] = y0; wps[wv][l8][1] = y1; wps[wv][l8][2] = y2; wps[wv][l8][3] = y3;
    wps[wv][l8][4] = q0; wps[wv][l8][5] = q1; wps[wv][l8][6] = q2; wps[wv][l8][7] = q3;
  }
  __syncthreads();
  if (t < 64){
    int tl8 = t >> 3, ti = t & 7;
    float v = wps[0][tl8][ti] + wps[1][tl8][ti] + wps[2][tl8][ti] + wps[3][tl8][ti];
    int col32 = tl8 * 4 + (ti & 3);
    if (ti < 4) pS[(size_t)blockIdx.x * 32 + col32] = v;
    else        pQ[(size_t)blockIdx.x * 32 + col32] = v;
  }
}

// ---------------- fold partials -> BN coeffs sc/sh (8 blocks, one per slice) ----------------
__global__ __launch_bounds__(1024) void redu_k(const float* pS, const float* pQ,
                                               const float* gg, const float* bb,
                                               float* sc, float* sh){
  __shared__ float ls[32][32], lq[32][32];
  int t = threadIdx.x;
  int slice = blockIdx.x;
  int grp = t >> 5, c32 = t & 31;
  float as = 0.f, aq = 0.f;
  for (int blk2 = grp; blk2 < NBLK2; blk2 += 32){
    size_t o = ((size_t)blk2 * 8 + slice) * 32 + c32;
    as += pS[o]; aq += pQ[o];
  }
  ls[grp][c32] = as; lq[grp][c32] = aq;
  __syncthreads();
  if (t < 32){
    float S = 0.f, Q = 0.f;
    #pragma unroll
    for (int gI = 0; gI < 32; ++gI){ S += ls[gI][t]; Q += lq[gI][t]; }
    int col = slice * 32 + t;
    const float invN = 1.0f / N_NODES;
    float mu = S * invN;
    float rs = rsqrtf(Q * invN - mu * mu + BN_EPS);
    float s = gg[col] * rs;
    sc[col] = s;
    sh[col] = bb[col] - s * mu;
  }
}

// ---------------- BN + LN apply (layer 1): h1 = LN(BN(g)) ----------------
__global__ __launch_bounds__(256) void apply1_k(const unsigned short* g, const float* sc, const float* sh,
                                                const float* lng, const float* lnb, unsigned short* h1){
  int lane = threadIdx.x & 63;
  int row = blockIdx.x * 4 + (threadIdx.x >> 6);
  if (row >= N_NODES) return;
  int c = lane * 4;
  float4 s4 = *(const float4*)(sc + c);
  float4 h4 = *(const float4*)(sh + c);
  uint2 u = *(const uint2*)(g + (size_t)row * H_DIM + c);
  float v0 = s4.x * bflo(u.x) + h4.x;
  float v1 = s4.y * bfhi(u.x) + h4.y;
  float v2 = s4.z * bflo(u.y) + h4.z;
  float v3 = s4.w * bfhi(u.y) + h4.w;
  float sum = wred(v0 + v1 + v2 + v3);
  float sq  = wred(v0*v0 + v1*v1 + v2*v2 + v3*v3);
  float mu = sum * (1.0f / H_DIM);
  float var = sq * (1.0f / H_DIM) - mu * mu;
  float rs = rsqrtf(var + LN_EPS);
  float4 g4 = *(const float4*)(lng + c);
  float4 b4 = *(const float4*)(lnb + c);
  float y0 = g4.x * (v0 - mu) * rs + b4.x;
  float y1 = g4.y * (v1 - mu) * rs + b4.y;
  float y2 = g4.z * (v2 - mu) * rs + b4.z;
  float y3 = g4.w * (v3 - mu) * rs + b4.w;
  uint2 o; o.x = pack2(y0, y1); o.y = pack2(y2, y3);
  *(uint2*)(h1 + (size_t)row * H_DIM + c) = o;
}

// ---------------- layer 2 apply + residual + output GEMM ----------------
__global__ __launch_bounds__(256) void apply2_k(const unsigned short* g, const float* sc, const float* sh,
                                                const float* lng, const float* lnb,
                                                const unsigned short* h1, const float* Wout,
                                                const float* bout, float* out){
  int lane = threadIdx.x & 63;
  int row = blockIdx.x * 4 + (threadIdx.x >> 6);
  if (row >= N_NODES) return;
  int c = lane * 4;
  float4 s4 = *(const float4*)(sc + c);
  float4 h4 = *(const float4*)(sh + c);
  uint2 u = *(const uint2*)(g + (size_t)row * H_DIM + c);
  float v0 = s4.x * bflo(u.x) + h4.x;
  float v1 = s4.y * bfhi(u.x) + h4.y;
  float v2 = s4.z * bflo(u.y) + h4.z;
  float v3 = s4.w * bfhi(u.y) + h4.w;
  float sum = wred(v0 + v1 + v2 + v3);
  float sq  = wred(v0*v0 + v1*v1 + v2*v2 + v3*v3);
  float mu = sum * (1.0f / H_DIM);
  float var = sq * (1.0f / H_DIM) - mu * mu;
  float rs = rsqrtf(var + LN_EPS);
  float4 g4 = *(const float4*)(lng + c);
  float4 b4 = *(const float4*)(lnb + c);
  uint2 hr = *(const uint2*)(h1 + (size_t)row * H_DIM + c);
  float y0 = g4.x * (v0 - mu) * rs + b4.x + bflo(hr.x);
  float y1 = g4.y * (v1 - mu) * rs + b4.y + bfhi(hr.x);
  float y2 = g4.z * (v2 - mu) * rs + b4.z + bflo(hr.y);
  float y3 = g4.w * (v3 - mu) * rs + b4.w + bfhi(hr.y);
  float4 w0 = *(const float4*)(Wout + c * 2);
  float4 w1 = *(const float4*)(Wout + c * 2 + 4);
  float o0 = y0 * w0.x + y1 * w0.z + y2 * w1.x + y3 * w1.z;
  float o1 = y0 * w0.y + y1 * w0.w + y2 * w1.y + y3 * w1.w;
  o0 = wred(o0); o1 = wred(o1);
  if (lane == 0){
    out[(size_t)row * 2 + 0] = o0 + bout[0];
    out[(size_t)row * 2 + 1] = o1 + bout[1];
  }
}

extern "C" void kernel_launch(void* const* d_in, const int* in_sizes, int n_in,
                              void* d_out, int out_size, void* d_ws, size_t ws_size,
                              hipStream_t stream) {
  const float* x    = (const float*)d_in[0];
  const int*   ei   = (const int*)d_in[1];
  const float* fs   = (const float*)d_in[2];
  const float* fb   = (const float*)d_in[3];
  const float* bn0g = (const float*)d_in[4];
  const float* bn0b = (const float*)d_in[5];
  const float* W1   = (const float*)d_in[6];
  const float* b1   = (const float*)d_in[7];
  const float* bn1g = (const float*)d_in[8];
  const float* bn1b = (const float*)d_in[9];
  const float* ln1g = (const float*)d_in[10];
  const float* ln1b = (const float*)d_in[11];
  const float* W2   = (const float*)d_in[12];
  const float* b2   = (const float*)d_in[13];
  const float* bn2g = (const float*)d_in[14];
  const float* bn2b = (const float*)d_in[15];
  const float* ln2g = (const float*)d_in[16];
  const float* ln2b = (const float*)d_in[17];
  const float* Wout = (const float*)d_in[18];
  const float* bout = (const float*)d_in[19];
  float* out = (float*)d_out;

  char* w = (char*)d_ws;
  // zeroed region: cnt + bn0 stat replicas + dhist
  int*   cnt   = (int*)(w + 0);            // 200000
  float* bn0S  = (float*)(w + 200000);     // [4][128] -> 202048
  float* bn0Q  = (float*)(w + 202048);     // -> 204096
  float* sc1   = (float*)(w + 204096);     // 1024 -> 205120
  float* sh1   = (float*)(w + 205120);     // 1024 -> 206144
  float* sc2   = (float*)(w + 206144);     // 1024 -> 207168
  float* sh2   = (float*)(w + 207168);     // 1024 -> 208192
  int*   dhist = (int*)(w + 208192);       // 256 -> 208448
  const size_t ZERO_BYTES = 208448;
  int*   dcur  = (int*)(w + 208448);       // 256 -> 208704
  int*   bsum  = (int*)(w + 208704);       // 1024 -> 209728
  int*   bpre  = (int*)(w + 209728);       // 1024 -> 210752, pad -> 210752
  float* dinv  = (float*)(w + 210752);     // 200000 -> 410752
  int*   offs  = (int*)(w + 410752);       // 200004 -> pad 610816
  int*   curs  = (int*)(w + 610816);       // 200000 -> 810816
  int*   perm  = (int*)(w + 810816);       // 200000 -> 1010816
  int*   rank  = (int*)(w + 1010816);      // 200000 -> 1210816, pad -> 1210880
  unsigned short* edges = (unsigned short*)(w + 1210880); // 1600000 -> 2810880, pad -> 2810944
  unsigned short* xt   = (unsigned short*)(w + 2810944);   // 12.8 MB -> 15610944
  unsigned short* W1t  = (unsigned short*)(w + 15610944);  // 64 KB  -> 15676480
  unsigned short* W2t  = (unsigned short*)(w + 15676480);  // 128 KB -> 15807552
  unsigned short* hlin = (unsigned short*)(w + 15807552);  // 25.6 MB (slice-major, dinv-prescaled)
  unsigned short* gbuf = (unsigned short*)(w + 41407552);  // 25.6 MB (row-major)
  unsigned short* h1   = (unsigned short*)(w + 67007552);  // 25.6 MB -> 92607552
  float* pS    = (float*)(w + 92607552);   // 12504*32*4 = 1600512 -> 94208064
  float* pQ    = (float*)(w + 94208064);   // 1600512 -> 95808576

  (void)in_sizes; (void)n_in; (void)out_size; (void)ws_size;

  hipMemsetAsync(d_ws, 0, ZERO_BYTES, stream);

  // graph preprocessing: degree -> degree-sort relabeling -> sorted CSR
  deg_k<<<(N_EDGES + 255) / 256, 256, 0, stream>>>(ei, cnt);
  hist_k<<<NBLK_HIST, 256, 0, stream>>>(cnt, dhist);
  dscan_k<<<1, 64, 0, stream>>>(dhist, dcur);
  dperm_k<<<NBLK_HIST, 256, 0, stream>>>(cnt, dcur, perm, rank);
  blocksum_k<<<NBLK_SCAN, 256, 0, stream>>>(cnt, perm, bsum);
  bscan_k<<<1, 256, 0, stream>>>(bsum, bpre, offs);
  cscan_k<<<NBLK_SCAN, 256, 0, stream>>>(cnt, perm, bpre, offs, curs, dinv);
  csr_k<<<(N_EDGES + 255) / 256, 256, 0, stream>>>(ei, rank, curs, edges);

  // input transform + BN0 folded
  bn0stats_k<<<128, 256, 0, stream>>>(x, fs, fb, bn0S, bn0Q);
  prepx_k<<<(N_NODES * 32) / 256, 256, 0, stream>>>(x, bn0S, bn0Q, fs, fb, bn0g, bn0b, xt);
  transpose2_k<<<(H_DIM * H_DIM + 255) / 256, 256, 0, stream>>>(W1, W2, W1t, W2t);

  int ggrid = (N_NODES + 63) / 64;
  int agg_blocks = NBLK2 * 8;

  // ---- layer 1 ----
  gemm_k<D_IN><<<ggrid, 256, 0, stream>>>(xt, W1t, dinv, hlin, N_NODES);
  agg_k<<<agg_blocks, 256, 0, stream>>>(hlin, offs, edges, perm, dinv, b1, gbuf, pS, pQ);
  redu_k<<<8, 1024, 0, stream>>>(pS, pQ, bn1g, bn1b, sc1, sh1);
  apply1_k<<<(N_NODES + 3) / 4, 256, 0, stream>>>(gbuf, sc1, sh1, ln1g, ln1b, h1);

  // ---- layer 2 ----
  gemm_k<H_DIM><<<ggrid, 256, 0, stream>>>(h1, W2t, dinv, hlin, N_NODES);
  agg_k<<<agg_blocks, 256, 0, stream>>>(hlin, offs, edges, perm, dinv, b2, gbuf, pS, pQ);
  redu_k<<<8, 1024, 0, stream>>>(pS, pQ, bn2g, bn2b, sc2, sh2);
  apply2_k<<<(N_NODES + 3) / 4, 256, 0, stream>>>(gbuf, sc2, sh2, ln2g, ln2b, h1, Wout, bout, out);
}

// Round 16
// 413.809 us; speedup vs baseline: 2.2850x; 1.0373x over previous
//
#include <hip/hip_runtime.h>
#include <hip/hip_bf16.h>
#include <stdint.h>

#define N_NODES 50000
#define N_EDGES 800000
#define D_IN    128
#define H_DIM   256
#define BN_EPS  1e-5f
#define LN_EPS  1e-5f
#define NBLK_SCAN 196  // ceil(50000/256)
#define NBLK_HIST 32
#define NBLK2 1563     // ceil(50000/32) node-groups for agg
#define SLICE_ELEMS ((size_t)N_NODES * 32)
#define EDGE_CHUNK 3072
#define DEG_BLOCKS 3125   // ceil(800000/256)
#define BN0_BLOCKS 128
#define PREPX_BLOCKS 6250 // N*32/256
#define TR_BLOCKS 256     // 65536/256

typedef float v4f __attribute__((ext_vector_type(4)));
typedef short v8s __attribute__((ext_vector_type(8)));

__device__ __forceinline__ float bflo(unsigned u){ return __uint_as_float(u << 16); }
__device__ __forceinline__ float bfhi(unsigned u){ return __uint_as_float(u & 0xffff0000u); }
__device__ __forceinline__ unsigned short f2bf(float f){
  unsigned u = __float_as_uint(f);
  u += 0x7fffu + ((u >> 16) & 1u);
  return (unsigned short)(u >> 16);
}
__device__ __forceinline__ unsigned pack2(float a, float b){
  return (unsigned)f2bf(a) | ((unsigned)f2bf(b) << 16);
}
__device__ __forceinline__ float wred(float v){
  #pragma unroll
  for (int m = 1; m < 64; m <<= 1) v += __shfl_xor(v, m, 64);
  return v;
}

__device__ __forceinline__ int block_excl_scan(int v){
  int t = threadIdx.x;
  int lane = t & 63, w = t >> 6;
  int inc = v;
  #pragma unroll
  for (int m = 1; m < 64; m <<= 1){
    int o = __shfl_up(inc, m, 64);
    if (lane >= m) inc += o;
  }
  __shared__ int wsum[4];
  if (lane == 63) wsum[w] = inc;
  __syncthreads();
  int base = 0;
  #pragma unroll
  for (int j = 0; j < 4; ++j) if (j < w) base += wsum[j];
  return base + inc - v;  // exclusive
}

// ---------------- fused: degree count (blocks >=128) || BN0 stats (blocks 0..127) ----------------
__global__ __launch_bounds__(256) void degbn_k(const int* ei, const float* x,
                                               const float* fs, const float* fb,
                                               int* cnt, float* S, float* Q){
  int b = blockIdx.x, t = threadIdx.x;
  if (b >= BN0_BLOCKS){
    int e = (b - BN0_BLOCKS) * 256 + t;
    if (e < N_EDGES) atomicAdd(&cnt[ei[N_EDGES + e]], 1);
    return;
  }
  int cl = t & 31, rg = t >> 5;
  int c = cl * 4;
  float4 fs4 = *(const float4*)(fs + c);
  float4 fb4 = *(const float4*)(fb + c);
  float s0=0,s1=0,s2=0,s3=0,q0=0,q1=0,q2=0,q3=0;
  for (int row = b * 8 + rg; row < N_NODES; row += BN0_BLOCKS * 8){
    float4 xv = *(const float4*)(x + (size_t)row * D_IN + c);
    float v0 = xv.x * fs4.x + fb4.x;
    float v1 = xv.y * fs4.y + fb4.y;
    float v2 = xv.z * fs4.z + fb4.z;
    float v3 = xv.w * fs4.w + fb4.w;
    s0 += v0; s1 += v1; s2 += v2; s3 += v3;
    q0 += v0*v0; q1 += v1*v1; q2 += v2*v2; q3 += v3*v3;
  }
  __shared__ float red[256][8];
  red[t][0]=s0; red[t][1]=s1; red[t][2]=s2; red[t][3]=s3;
  red[t][4]=q0; red[t][5]=q1; red[t][6]=q2; red[t][7]=q3;
  __syncthreads();
  float* Sr = S + (b & 3) * D_IN;
  float* Qr = Q + (b & 3) * D_IN;
  if (t < 32){
    float a[8];
    #pragma unroll
    for (int i = 0; i < 8; ++i) a[i] = red[t][i];
    for (int j = 1; j < 8; ++j)
      #pragma unroll
      for (int i = 0; i < 8; ++i) a[i] += red[t + 32*j][i];
    #pragma unroll
    for (int i = 0; i < 4; ++i){ atomicAdd(&Sr[t*4+i], a[i]); atomicAdd(&Qr[t*4+i], a[4+i]); }
  }
}

__global__ __launch_bounds__(256) void hist_k(const int* cnt, int* dhist){
  __shared__ int lh[64];
  int t = threadIdx.x;
  if (t < 64) lh[t] = 0;
  __syncthreads();
  for (int i = blockIdx.x * 256 + t; i < N_NODES; i += NBLK_HIST * 256)
    atomicAdd(&lh[min(cnt[i], 63)], 1);
  __syncthreads();
  if (t < 64 && lh[t] > 0) atomicAdd(&dhist[t], lh[t]);
}

// counting-sort with in-block dhist prefix (dscan folded); 'reserve' zero-initialized
__global__ __launch_bounds__(256) void dperm_k(const int* cnt, const int* dhist, int* reserve,
                                               int* perm, int* rank){
  __shared__ int ep_s[64];
  __shared__ int lh[64], lb[64], lc[64];
  int t = threadIdx.x;
  if (t < 64){
    int v = dhist[t];
    int inc = v;
    #pragma unroll
    for (int m = 1; m < 64; m <<= 1){
      int o = __shfl_up(inc, m, 64);
      if (t >= m) inc += o;
    }
    ep_s[t] = inc - v;  // global exclusive bin prefix
    lh[t] = 0; lc[t] = 0;
  }
  __syncthreads();
  for (int i = blockIdx.x * 256 + t; i < N_NODES; i += NBLK_HIST * 256)
    atomicAdd(&lh[min(cnt[i], 63)], 1);
  __syncthreads();
  if (t < 64 && lh[t] > 0) lb[t] = ep_s[t] + atomicAdd(&reserve[t], lh[t]);
  __syncthreads();
  for (int i = blockIdx.x * 256 + t; i < N_NODES; i += NBLK_HIST * 256){
    int b = min(cnt[i], 63);
    int r = atomicAdd(&lc[b], 1);
    int pos = lb[b] + r;
    perm[pos] = i;
    rank[i] = pos;
  }
}

__global__ __launch_bounds__(256) void blocksum_k(const int* cnt, const int* perm, int* bsum){
  int i = blockIdx.x * 256 + threadIdx.x;
  int v = (i < N_NODES) ? cnt[perm[i]] : 0;
  #pragma unroll
  for (int m = 1; m < 64; m <<= 1) v += __shfl_xor(v, m, 64);
  __shared__ int ws[4];
  int t = threadIdx.x;
  if ((t & 63) == 0) ws[t >> 6] = v;
  __syncthreads();
  if (t == 0) bsum[blockIdx.x] = ws[0] + ws[1] + ws[2] + ws[3];
}

__global__ __launch_bounds__(256) void bscan_k(const int* bsum, int* bpre, int* offs){
  int t = threadIdx.x;
  int v = (t < NBLK_SCAN) ? bsum[t] : 0;
  int e = block_excl_scan(v);
  if (t < NBLK_SCAN) bpre[t] = e;
  if (t == 0) offs[N_NODES] = N_EDGES;
}

__global__ __launch_bounds__(256) void cscan_k(const int* cnt, const int* perm, const int* bpre,
                                               int* offs, int* curs, float* dinv){
  int t = threadIdx.x;
  int i = blockIdx.x * 256 + t;
  int node = 0, v = 0;
  if (i < N_NODES){ node = perm[i]; v = cnt[node]; }
  int e = block_excl_scan(v) + bpre[blockIdx.x];
  if (i < N_NODES){
    offs[i] = e; curs[i] = e;
    dinv[node] = rsqrtf((float)v + 1.0f);
  }
}

// ---------------- fused: csr scatter || prepx (BN0 apply + bf16 cast) || weight transpose ----------------
__global__ __launch_bounds__(256) void csrprep_k(const int* ei, const int* rank, int* cursor,
                                                 unsigned short* edges,
                                                 const float* x, const float* S, const float* Q,
                                                 const float* fs, const float* fb,
                                                 const float* gg, const float* bb,
                                                 unsigned short* xt,
                                                 const float* W1, const float* W2,
                                                 unsigned short* W1t, unsigned short* W2t){
  int b = blockIdx.x, t = threadIdx.x;
  if (b < DEG_BLOCKS){
    int e = b * 256 + t;
    if (e < N_EDGES){
      int s = ei[e], d = ei[N_EDGES + e];
      int p = atomicAdd(&cursor[rank[d]], 1);
      edges[p] = (unsigned short)s;
    }
    return;
  }
  if (b < DEG_BLOCKS + PREPX_BLOCKS){
    int i = (b - DEG_BLOCKS) * 256 + t;
    int row = i >> 5; int c = (i & 31) * 4;
    float4 Sv = *(const float4*)(S + c);
    float4 Qv = *(const float4*)(Q + c);
    #pragma unroll
    for (int rep = 1; rep < 4; ++rep){
      float4 s2 = *(const float4*)(S + rep * D_IN + c);
      float4 q2 = *(const float4*)(Q + rep * D_IN + c);
      Sv.x += s2.x; Sv.y += s2.y; Sv.z += s2.z; Sv.w += s2.w;
      Qv.x += q2.x; Qv.y += q2.y; Qv.z += q2.z; Qv.w += q2.w;
    }
    float4 fs4 = *(const float4*)(fs + c);
    float4 fb4 = *(const float4*)(fb + c);
    float4 gg4 = *(const float4*)(gg + c);
    float4 bb4 = *(const float4*)(bb + c);
    const float invN = 1.0f / N_NODES;
    float mu0 = Sv.x*invN, mu1 = Sv.y*invN, mu2 = Sv.z*invN, mu3 = Sv.w*invN;
    float r0 = rsqrtf(Qv.x*invN - mu0*mu0 + BN_EPS);
    float r1 = rsqrtf(Qv.y*invN - mu1*mu1 + BN_EPS);
    float r2 = rsqrtf(Qv.z*invN - mu2*mu2 + BN_EPS);
    float r3 = rsqrtf(Qv.w*invN - mu3*mu3 + BN_EPS);
    float a0 = gg4.x*r0*fs4.x, c0 = gg4.x*r0*(fb4.x - mu0) + bb4.x;
    float a1 = gg4.y*r1*fs4.y, c1 = gg4.y*r1*(fb4.y - mu1) + bb4.y;
    float a2 = gg4.z*r2*fs4.z, c2 = gg4.z*r2*(fb4.z - mu2) + bb4.z;
    float a3 = gg4.w*r3*fs4.w, c3 = gg4.w*r3*(fb4.w - mu3) + bb4.w;
    float4 xv = *(const float4*)(x + (size_t)row * D_IN + c);
    uint2 o;
    o.x = pack2(a0 * xv.x + c0, a1 * xv.y + c1);
    o.y = pack2(a2 * xv.z + c2, a3 * xv.w + c3);
    *(uint2*)(xt + (size_t)row * D_IN + c) = o;
    return;
  }
  int i = (b - DEG_BLOCKS - PREPX_BLOCKS) * 256 + t;
  if (i < D_IN * H_DIM){
    int r = i / H_DIM, c = i % H_DIM;
    W1t[c * D_IN + r] = f2bf(W1[i]);
  }
  if (i < H_DIM * H_DIM){
    int r = i / H_DIM, c = i % H_DIM;
    W2t[c * H_DIM + r] = f2bf(W2[i]);
  }
}

// ---------------- bf16 MFMA GEMM: 64x256 tile, C = dinv[row]*(A@Bt^T), slice-major ----------------
template<int K>
__global__ __launch_bounds__(256) void gemm_k(const unsigned short* A, const unsigned short* Bt,
                                              const float* dinv, unsigned short* C, int M){
  __shared__ __align__(16) short smem[16896];
  __shared__ float dvs[64];
  short* As = smem;               // [64][40]
  short* Bs = smem + 64 * 40;     // [256][40]
  int t = threadIdx.x;
  int m0 = blockIdx.x * 64;
  int lane = t & 63;
  int w = t >> 6;
  int fr = lane & 15, quad = lane >> 4;
  if (t < 64) dvs[t] = (m0 + t < M) ? dinv[m0 + t] : 0.0f;
  v4f acc[4][4] = {};
  int sr = t >> 2;
  int sk = (t & 3) << 3;
  for (int k0 = 0; k0 < K; k0 += 32){
    __syncthreads();
    uint4 av = {0,0,0,0};
    int arow = m0 + sr;
    if (arow < M) av = *(const uint4*)(A + (size_t)arow * K + k0 + sk);
    *(uint4*)(&As[sr * 40 + sk]) = av;
    #pragma unroll
    for (int j = 0; j < 4; ++j){
      int brow = sr + 64 * j;
      uint4 bv = *(const uint4*)(Bt + (size_t)brow * K + k0 + sk);
      *(uint4*)(&Bs[brow * 40 + sk]) = bv;
    }
    __syncthreads();
    v8s af[4], bf[4];
    #pragma unroll
    for (int mi = 0; mi < 4; ++mi)
      af[mi] = *(const v8s*)(&As[(mi * 16 + fr) * 40 + quad * 8]);
    #pragma unroll
    for (int ni = 0; ni < 4; ++ni)
      bf[ni] = *(const v8s*)(&Bs[(w * 64 + ni * 16 + fr) * 40 + quad * 8]);
    #pragma unroll
    for (int mi = 0; mi < 4; ++mi)
      #pragma unroll
      for (int ni = 0; ni < 4; ++ni)
        acc[mi][ni] = __builtin_amdgcn_mfma_f32_16x16x32_bf16(af[mi], bf[ni], acc[mi][ni], 0, 0, 0);
  }
  __syncthreads();
  short* Cs = smem; // [64][264]
  #pragma unroll
  for (int mi = 0; mi < 4; ++mi)
    #pragma unroll
    for (int ni = 0; ni < 4; ++ni)
      #pragma unroll
      for (int r = 0; r < 4; ++r){
        int row = mi * 16 + quad * 4 + r;
        int col = w * 64 + ni * 16 + fr;
        Cs[row * 264 + col] = (short)f2bf(acc[mi][ni][r] * dvs[row]);
      }
  __syncthreads();
  int orow = t >> 2;
  int grow = m0 + orow;
  if (grow < M){
    #pragma unroll
    for (int j = 0; j < 4; ++j){
      int oc = (t & 3) * 16 + 64 * j;
      v8s v0 = *(const v8s*)(&Cs[orow * 264 + oc]);
      v8s v1 = *(const v8s*)(&Cs[orow * 264 + oc + 8]);
      *(v8s*)(&C[(size_t)(oc >> 5) * SLICE_ELEMS + (size_t)grow * 32 + (oc & 31)]) = v0;
      int oc1 = oc + 8;
      *(v8s*)(&C[(size_t)(oc1 >> 5) * SLICE_ELEMS + (size_t)grow * 32 + (oc1 & 31)]) = v1;
    }
  }
}

// ---------------- edge aggregation + fused column-stat partials, 16-deep gather unroll ----------------
__global__ __launch_bounds__(256) void agg_k(const unsigned short* hs, const int* offsets,
                                             const unsigned short* edges, const int* perm,
                                             const float* dinv, const float* bias,
                                             unsigned short* g, float* pS, float* pQ){
  __shared__ unsigned eds32[EDGE_CHUNK / 2];
  __shared__ float wps[4][8][8];
  int t = threadIdx.x;
  int lane = t & 63;
  int wv = t >> 6;
  int slice = blockIdx.x & 7;
  int l8 = lane & 7;
  int nb = (blockIdx.x >> 3) * 32;
  int idx = nb + (t >> 3);
  int lastn = min(nb + 32, N_NODES);
  int blk0 = offsets[nb];
  int base = blk0 & ~1;
  int blkN = offsets[lastn];
  const unsigned* gsrc = (const unsigned*)(edges + base);
  int nu = min((blkN - base + 1) >> 1, EDGE_CHUNK / 2);
  for (int i = t; i < nu; i += 256)
    eds32[i] = gsrc[i];
  __syncthreads();
  bool act = idx < N_NODES;
  int node = act ? perm[idx] : 0;
  const unsigned short* hb = hs + (size_t)slice * SLICE_ELEMS;
  float4 bb = *(const float4*)(bias + slice * 32 + l8 * 4);
  uint2 sv = *(const uint2*)(hb + (size_t)node * 32 + l8 * 4);
  float a0 = bflo(sv.x), a1 = bfhi(sv.x);
  float a2 = bflo(sv.y), a3 = bfhi(sv.y);
  int e  = act ? offsets[idx] : 0;
  int e1 = act ? offsets[idx + 1] : 0;
  if ((e & 1) && e < e1){
    int ru = (e - base) >> 1;
    unsigned d = (ru < EDGE_CHUNK / 2) ? eds32[ru] : gsrc[ru];
    unsigned s = d >> 16;
    uint2 v = *(const uint2*)(hb + (size_t)s * 32 + l8 * 4);
    a0 += bflo(v.x); a1 += bfhi(v.x);
    a2 += bflo(v.y); a3 += bfhi(v.y);
    ++e;
  }
  // 16 edges per iteration: 8 uint LDS reads -> 16 independent gathers in flight
  for (; e + 16 <= e1; e += 16){
    int ru = (e - base) >> 1;
    unsigned dd[8];
    if (ru + 8 <= EDGE_CHUNK / 2){
      #pragma unroll
      for (int j = 0; j < 8; ++j) dd[j] = eds32[ru + j];
    } else {
      #pragma unroll
      for (int j = 0; j < 8; ++j) dd[j] = gsrc[ru + j];
    }
    uint2 v[16];
    #pragma unroll
    for (int j = 0; j < 8; ++j){
      v[2*j]   = *(const uint2*)(hb + (size_t)(dd[j] & 0xffffu) * 32 + l8 * 4);
      v[2*j+1] = *(const uint2*)(hb + (size_t)(dd[j] >> 16)     * 32 + l8 * 4);
    }
    #pragma unroll
    for (int j = 0; j < 16; ++j){
      a0 += bflo(v[j].x); a1 += bfhi(v[j].x);
      a2 += bflo(v[j].y); a3 += bfhi(v[j].y);
    }
  }
  // 8-edge block
  if (e + 8 <= e1){
    int ru = (e - base) >> 1;
    unsigned dd[4];
    if (ru + 4 <= EDGE_CHUNK / 2){
      #pragma unroll
      for (int j = 0; j < 4; ++j) dd[j] = eds32[ru + j];
    } else {
      #pragma unroll
      for (int j = 0; j < 4; ++j) dd[j] = gsrc[ru + j];
    }
    uint2 v[8];
    #pragma unroll
    for (int j = 0; j < 4; ++j){
      v[2*j]   = *(const uint2*)(hb + (size_t)(dd[j] & 0xffffu) * 32 + l8 * 4);
      v[2*j+1] = *(const uint2*)(hb + (size_t)(dd[j] >> 16)     * 32 + l8 * 4);
    }
    #pragma unroll
    for (int j = 0; j < 8; ++j){
      a0 += bflo(v[j].x); a1 += bfhi(v[j].x);
      a2 += bflo(v[j].y); a3 += bfhi(v[j].y);
    }
    e += 8;
  }
  for (; e < e1; ++e){
    int r = e - base;
    unsigned d = ((r >> 1) < EDGE_CHUNK / 2) ? eds32[r >> 1] : gsrc[r >> 1];
    unsigned s = (r & 1) ? (d >> 16) : (d & 0xffffu);
    uint2 v = *(const uint2*)(hb + (size_t)s * 32 + l8 * 4);
    a0 += bflo(v.x); a1 += bfhi(v.x);
    a2 += bflo(v.y); a3 += bfhi(v.y);
  }
  float dv = dinv[node];
  float y0 = act ? fmaxf(dv * a0 + bb.x, 0.f) : 0.f;
  float y1 = act ? fmaxf(dv * a1 + bb.y, 0.f) : 0.f;
  float y2 = act ? fmaxf(dv * a2 + bb.z, 0.f) : 0.f;
  float y3 = act ? fmaxf(dv * a3 + bb.w, 0.f) : 0.f;
  if (act){
    uint2 o;
    o.x = pack2(y0, y1); o.y = pack2(y2, y3);
    *(uint2*)(g + (size_t)node * H_DIM + slice * 32 + l8 * 4) = o;
  }
  float q0 = y0*y0, q1 = y1*y1, q2 = y2*y2, q3 = y3*y3;
  #pragma unroll
  for (int m = 8; m < 64; m <<= 1){
    y0 += __shfl_xor(y0, m, 64); y1 += __shfl_xor(y1, m, 64);
    y2 += __shfl_xor(y2, m, 64); y3 += __shfl_xor(y3, m, 64);
    q0 += __shfl_xor(q0, m, 64); q1 += __shfl_xor(q1, m, 64);
    q2 += __shfl_xor(q2, m, 64); q3 += __shfl_xor(q3, m, 64);
  }
  if (lane < 8){
    wps[wv][l8][0] = y0; wps[wv][l8][1] = y1; wps[wv][l8][2] = y2; wps[wv][l8][3] = y3;
    wps[wv][l8][4] = q0; wps[wv][l8][5] = q1; wps[wv][l8][6] = q2; wps[wv][l8][7] = q3;
  }
  __syncthreads();
  if (t < 64){
    int tl8 = t >> 3, ti = t & 7;
    float v = wps[0][tl8][ti] + wps[1][tl8][ti] + wps[2][tl8][ti] + wps[3][tl8][ti];
    int col32 = tl8 * 4 + (ti & 3);
    if (ti < 4) pS[(size_t)blockIdx.x * 32 + col32] = v;
    else        pQ[(size_t)blockIdx.x * 32 + col32] = v;
  }
}

// ---------------- fold partials -> BN coeffs sc/sh (8 blocks, one per slice) ----------------
__global__ __launch_bounds__(1024) void redu_k(const float* pS, const float* pQ,
                                               const float* gg, const float* bb,
                                               float* sc, float* sh){
  __shared__ float ls[32][32], lq[32][32];
  int t = threadIdx.x;
  int slice = blockIdx.x;
  int grp = t >> 5, c32 = t & 31;
  float as = 0.f, aq = 0.f;
  for (int blk2 = grp; blk2 < NBLK2; blk2 += 32){
    size_t o = ((size_t)blk2 * 8 + slice) * 32 + c32;
    as += pS[o]; aq += pQ[o];
  }
  ls[grp][c32] = as; lq[grp][c32] = aq;
  __syncthreads();
  if (t < 32){
    float S = 0.f, Q = 0.f;
    #pragma unroll
    for (int gI = 0; gI < 32; ++gI){ S += ls[gI][t]; Q += lq[gI][t]; }
    int col = slice * 32 + t;
    const float invN = 1.0f / N_NODES;
    float mu = S * invN;
    float rs = rsqrtf(Q * invN - mu * mu + BN_EPS);
    float s = gg[col] * rs;
    sc[col] = s;
    sh[col] = bb[col] - s * mu;
  }
}

// ---------------- BN + LN apply (layer 1): h1 = LN(BN(g)) ----------------
__global__ __launch_bounds__(256) void apply1_k(const unsigned short* g, const float* sc, const float* sh,
                                                const float* lng, const float* lnb, unsigned short* h1){
  int lane = threadIdx.x & 63;
  int row = blockIdx.x * 4 + (threadIdx.x >> 6);
  if (row >= N_NODES) return;
  int c = lane * 4;
  float4 s4 = *(const float4*)(sc + c);
  float4 h4 = *(const float4*)(sh + c);
  uint2 u = *(const uint2*)(g + (size_t)row * H_DIM + c);
  float v0 = s4.x * bflo(u.x) + h4.x;
  float v1 = s4.y * bfhi(u.x) + h4.y;
  float v2 = s4.z * bflo(u.y) + h4.z;
  float v3 = s4.w * bfhi(u.y) + h4.w;
  float sum = wred(v0 + v1 + v2 + v3);
  float sq  = wred(v0*v0 + v1*v1 + v2*v2 + v3*v3);
  float mu = sum * (1.0f / H_DIM);
  float var = sq * (1.0f / H_DIM) - mu * mu;
  float rs = rsqrtf(var + LN_EPS);
  float4 g4 = *(const float4*)(lng + c);
  float4 b4 = *(const float4*)(lnb + c);
  float y0 = g4.x * (v0 - mu) * rs + b4.x;
  float y1 = g4.y * (v1 - mu) * rs + b4.y;
  float y2 = g4.z * (v2 - mu) * rs + b4.z;
  float y3 = g4.w * (v3 - mu) * rs + b4.w;
  uint2 o; o.x = pack2(y0, y1); o.y = pack2(y2, y3);
  *(uint2*)(h1 + (size_t)row * H_DIM + c) = o;
}

// ---------------- layer 2 apply + residual + output GEMM ----------------
__global__ __launch_bounds__(256) void apply2_k(const unsigned short* g, const float* sc, const float* sh,
                                                const float* lng, const float* lnb,
                                                const unsigned short* h1, const float* Wout,
                                                const float* bout, float* out){
  int lane = threadIdx.x & 63;
  int row = blockIdx.x * 4 + (threadIdx.x >> 6);
  if (row >= N_NODES) return;
  int c = lane * 4;
  float4 s4 = *(const float4*)(sc + c);
  float4 h4 = *(const float4*)(sh + c);
  uint2 u = *(const uint2*)(g + (size_t)row * H_DIM + c);
  float v0 = s4.x * bflo(u.x) + h4.x;
  float v1 = s4.y * bfhi(u.x) + h4.y;
  float v2 = s4.z * bflo(u.y) + h4.z;
  float v3 = s4.w * bfhi(u.y) + h4.w;
  float sum = wred(v0 + v1 + v2 + v3);
  float sq  = wred(v0*v0 + v1*v1 + v2*v2 + v3*v3);
  float mu = sum * (1.0f / H_DIM);
  float var = sq * (1.0f / H_DIM) - mu * mu;
  float rs = rsqrtf(var + LN_EPS);
  float4 g4 = *(const float4*)(lng + c);
  float4 b4 = *(const float4*)(lnb + c);
  uint2 hr = *(const uint2*)(h1 + (size_t)row * H_DIM + c);
  float y0 = g4.x * (v0 - mu) * rs + b4.x + bflo(hr.x);
  float y1 = g4.y * (v1 - mu) * rs + b4.y + bfhi(hr.x);
  float y2 = g4.z * (v2 - mu) * rs + b4.z + bflo(hr.y);
  float y3 = g4.w * (v3 - mu) * rs + b4.w + bfhi(hr.y);
  float4 w0 = *(const float4*)(Wout + c * 2);
  float4 w1 = *(const float4*)(Wout + c * 2 + 4);
  float o0 = y0 * w0.x + y1 * w0.z + y2 * w1.x + y3 * w1.z;
  float o1 = y0 * w0.y + y1 * w0.w + y2 * w1.y + y3 * w1.w;
  o0 = wred(o0); o1 = wred(o1);
  if (lane == 0){
    out[(size_t)row * 2 + 0] = o0 + bout[0];
    out[(size_t)row * 2 + 1] = o1 + bout[1];
  }
}

extern "C" void kernel_launch(void* const* d_in, const int* in_sizes, int n_in,
                              void* d_out, int out_size, void* d_ws, size_t ws_size,
                              hipStream_t stream) {
  const float* x    = (const float*)d_in[0];
  const int*   ei   = (const int*)d_in[1];
  const float* fs   = (const float*)d_in[2];
  const float* fb   = (const float*)d_in[3];
  const float* bn0g = (const float*)d_in[4];
  const float* bn0b = (const float*)d_in[5];
  const float* W1   = (const float*)d_in[6];
  const float* b1   = (const float*)d_in[7];
  const float* bn1g = (const float*)d_in[8];
  const float* bn1b = (const float*)d_in[9];
  const float* ln1g = (const float*)d_in[10];
  const float* ln1b = (const float*)d_in[11];
  const float* W2   = (const float*)d_in[12];
  const float* b2   = (const float*)d_in[13];
  const float* bn2g = (const float*)d_in[14];
  const float* bn2b = (const float*)d_in[15];
  const float* ln2g = (const float*)d_in[16];
  const float* ln2b = (const float*)d_in[17];
  const float* Wout = (const float*)d_in[18];
  const float* bout = (const float*)d_in[19];
  float* out = (float*)d_out;

  char* w = (char*)d_ws;
  int*   cnt   = (int*)(w + 0);            // 200000
  float* bn0S  = (float*)(w + 200000);     // [4][128] -> 202048
  float* bn0Q  = (float*)(w + 202048);     // -> 204096
  float* sc1   = (float*)(w + 204096);     // 1024 -> 205120
  float* sh1   = (float*)(w + 205120);     // -> 206144
  float* sc2   = (float*)(w + 206144);     // -> 207168
  float* sh2   = (float*)(w + 207168);     // -> 208192
  int*   dhist = (int*)(w + 208192);       // 256 -> 208448
  int*   reserve = (int*)(w + 208448);     // 256 -> 208704
  const size_t ZERO_BYTES = 208704;
  int*   bsum  = (int*)(w + 208704);       // 1024 -> 209728
  int*   bpre  = (int*)(w + 209728);       // 1024 -> 210752
  float* dinv  = (float*)(w + 210752);     // 200000 -> 410752
  int*   offs  = (int*)(w + 410752);       // 200004 -> pad 610816
  int*   curs  = (int*)(w + 610816);       // 200000 -> 810816
  int*   perm  = (int*)(w + 810816);       // 200000 -> 1010816
  int*   rank  = (int*)(w + 1010816);      // 200000 -> 1210816 pad 1210880
  unsigned short* edges = (unsigned short*)(w + 1210880); // 1600000 -> pad 2810944
  unsigned short* xt   = (unsigned short*)(w + 2810944);   // 12.8 MB -> 15610944
  unsigned short* W1t  = (unsigned short*)(w + 15610944);  // -> 15676480
  unsigned short* W2t  = (unsigned short*)(w + 15676480);  // -> 15807552
  unsigned short* hlin = (unsigned short*)(w + 15807552);  // 25.6 MB
  unsigned short* gbuf = (unsigned short*)(w + 41407552);  // 25.6 MB
  unsigned short* h1   = (unsigned short*)(w + 67007552);  // 25.6 MB -> 92607552
  float* pS    = (float*)(w + 92607552);   // 1600512 -> 94208064
  float* pQ    = (float*)(w + 94208064);   // 1600512 -> 95808576

  (void)in_sizes; (void)n_in; (void)out_size; (void)ws_size;

  hipMemsetAsync(d_ws, 0, ZERO_BYTES, stream);

  // fused preprocessing
  degbn_k<<<BN0_BLOCKS + DEG_BLOCKS, 256, 0, stream>>>(ei, x, fs, fb, cnt, bn0S, bn0Q);
  hist_k<<<NBLK_HIST, 256, 0, stream>>>(cnt, dhist);
  dperm_k<<<NBLK_HIST, 256, 0, stream>>>(cnt, dhist, reserve, perm, rank);
  blocksum_k<<<NBLK_SCAN, 256, 0, stream>>>(cnt, perm, bsum);
  bscan_k<<<1, 256, 0, stream>>>(bsum, bpre, offs);
  cscan_k<<<NBLK_SCAN, 256, 0, stream>>>(cnt, perm, bpre, offs, curs, dinv);
  csrprep_k<<<DEG_BLOCKS + PREPX_BLOCKS + TR_BLOCKS, 256, 0, stream>>>(
      ei, rank, curs, edges, x, bn0S, bn0Q, fs, fb, bn0g, bn0b, xt, W1, W2, W1t, W2t);

  int ggrid = (N_NODES + 63) / 64;
  int agg_blocks = NBLK2 * 8;

  // ---- layer 1 ----
  gemm_k<D_IN><<<ggrid, 256, 0, stream>>>(xt, W1t, dinv, hlin, N_NODES);
  agg_k<<<agg_blocks, 256, 0, stream>>>(hlin, offs, edges, perm, dinv, b1, gbuf, pS, pQ);
  redu_k<<<8, 1024, 0, stream>>>(pS, pQ, bn1g, bn1b, sc1, sh1);
  apply1_k<<<(N_NODES + 3) / 4, 256, 0, stream>>>(gbuf, sc1, sh1, ln1g, ln1b, h1);

  // ---- layer 2 ----
  gemm_k<H_DIM><<<ggrid, 256, 0, stream>>>(h1, W2t, dinv, hlin, N_NODES);
  agg_k<<<agg_blocks, 256, 0, stream>>>(hlin, offs, edges, perm, dinv, b2, gbuf, pS, pQ);
  redu_k<<<8, 1024, 0, stream>>>(pS, pQ, bn2g, bn2b, sc2, sh2);
  apply2_k<<<(N_NODES + 3) / 4, 256, 0, stream>>>(gbuf, sc2, sh2, ln2g, ln2b, h1, Wout, bout, out);
}